// Round 9
// baseline (696.341 us; speedup 1.0000x reference)
//
#include <hip/hip_runtime.h>

typedef unsigned short u16;
typedef short short8 __attribute__((ext_vector_type(8)));
typedef float floatx4 __attribute__((ext_vector_type(4)));

__device__ __forceinline__ float b2f(u16 h) {
  union { unsigned int u; float f; } z;
  z.u = ((unsigned int)h) << 16;
  return z.f;
}
__device__ __forceinline__ u16 f2b(float f) {
  union { float f; unsigned int u; } z;
  z.f = f;
  unsigned int u = z.u;
  unsigned int r = (u + 0x7fffu + ((u >> 16) & 1u)) >> 16;
  return (u16)r;
}

// ---- global_load_lds staging of a 128x64 bf16 tile (16 KB), XOR-swizzled ----------
__device__ __forceinline__ void stage_tile64(const u16* __restrict__ gsrc, int lda,
                                             u16* lds, int wave, int lane) {
#pragma unroll
  for (int i = 0; i < 4; i++) {
    const int s = wave * 256 + i * 64 + lane;
    const int row = s >> 3;
    const int c8 = (s & 7) ^ (row & 7);
    const u16* g = gsrc + (long)row * lda + (c8 << 3);
    u16* l = lds + (wave * 256 + i * 64) * 8;  // wave-uniform
    __builtin_amdgcn_global_load_lds(
        (const __attribute__((address_space(1))) unsigned int*)g,
        (__attribute__((address_space(3))) unsigned int*)l, 16, 0, 0);
  }
}
// swizzled 16B fragment read: row in [0,128), slot in [0,8)
__device__ __forceinline__ short8 frag64(const u16* lds, int row, int slot) {
  return *(const short8*)(lds + (row << 6) + ((slot ^ (row & 7)) << 3));
}

// ---------------- merged cast fp32 -> bf16 for Wq | Wk | t_tok -----------------------
__global__ __launch_bounds__(256)
void cast3_kernel(const float* __restrict__ Wq, const float* __restrict__ Wk,
                  const float* __restrict__ tt, u16* __restrict__ Wq16,
                  u16* __restrict__ Wk16, u16* __restrict__ tt16) {
  const int blk = blockIdx.x;
  const float* src; u16* dst; long base;
  if (blk < 512) { src = Wq; dst = Wq16; base = (long)blk; }
  else if (blk < 896) { src = Wk; dst = Wk16; base = (long)(blk - 512); }
  else { src = tt; dst = tt16; base = (long)(blk - 896); }
  const long i = (base * 256 + threadIdx.x) * 8;
  float4 v0 = *(const float4*)(src + i);
  float4 v1 = *(const float4*)(src + i + 4);
  u16 r[8] __attribute__((aligned(16)));
  r[0] = f2b(v0.x); r[1] = f2b(v0.y); r[2] = f2b(v0.z); r[3] = f2b(v0.w);
  r[4] = f2b(v1.x); r[5] = f2b(v1.y); r[6] = f2b(v1.z); r[7] = f2b(v1.w);
  *(uint4*)(dst + i) = *(const uint4*)r;
}

// ---------------- transpose fp32 src (b,R,Cc) -> bf16 dst (b,Cc,R) ------------------
__global__ __launch_bounds__(256)
void transpose_f32(const float* __restrict__ src, u16* __restrict__ dst,
                   int R, int Cc, long sSrc, long sDst) {
  __shared__ u16 t[64][66];
  const int tid = threadIdx.x;
  const long r0 = (long)blockIdx.x << 6;
  const long c0 = (long)blockIdx.y << 6;
  const float* s = src + (long)blockIdx.z * sSrc;
  u16* d = dst + (long)blockIdx.z * sDst;
  const int rr = tid >> 2;
  const int cb = (tid & 3) << 2;  // 0,4,8,12
#pragma unroll
  for (int h = 0; h < 4; h++) {
    int cc = cb + h * 16;
    float4 v = *(const float4*)(s + (r0 + rr) * Cc + c0 + cc);
    t[rr][cc + 0] = f2b(v.x); t[rr][cc + 1] = f2b(v.y);
    t[rr][cc + 2] = f2b(v.z); t[rr][cc + 3] = f2b(v.w);
  }
  __syncthreads();
  const int cr = tid >> 2;
  const int nb0 = (tid & 3) << 3;
#pragma unroll
  for (int h = 0; h < 2; h++) {
    int rb = nb0 + h * 32;
    u16 res[8] __attribute__((aligned(16)));
#pragma unroll
    for (int j = 0; j < 8; j++) res[j] = t[rb + j][cr];
    *(uint4*)(d + (c0 + cr) * R + r0 + rb) = *(const uint4*)res;
  }
}

// ---------------- GEMM: C = alpha * A(row-major MxK) * B^T (B is NxK row-major) ------
// BK=64, global_load_lds staging, XOR-swizzled LDS. K must be a multiple of 64.
// OUT_MODE: 0 bf16 (direct store); 1 fp32; 3 fp32 + resid add. Modes 1/3 use an
// LDS-staged coalesced epilogue (float4 over contiguous 512B rows).
template <int BIAS_MODE, int OUT_MODE, bool BETA_ACC>
__global__ __launch_bounds__(256)
void gemm_nt(const u16* __restrict__ A, long sA, int lda,
             const u16* __restrict__ Bm, long sB, int ldb,
             void* __restrict__ Cv, long sC, int ldc,
             const float* __restrict__ bias, const float* __restrict__ resid,
             const float* __restrict__ alphap, float alphac, int K) {
  __shared__ __align__(16) char smem[33792];
  u16* As = (u16*)smem;
  u16* Bs = (u16*)(smem + 16384);
  float* scr = (float*)smem;  // epilogue scratch [64][132] (aliases As/Bs, dead then)
  const int tid = threadIdx.x;
  const long m0 = (long)blockIdx.x * 128;
  const long n0 = (long)blockIdx.y * 128;
  const u16* Ab = A + (long)blockIdx.z * sA + m0 * lda;
  const u16* Bb = Bm + (long)blockIdx.z * sB + n0 * ldb;
  const int wave = tid >> 6;
  const int lane = tid & 63;
  const int wr = (wave >> 1) << 6;
  const int wc = (wave & 1) << 6;
  const int quad = lane >> 4;
  const int lr = lane & 15;
  floatx4 acc[4][4] = {};
  for (int k0 = 0; k0 < K; k0 += 64) {
    __syncthreads();
    stage_tile64(Ab + k0, lda, As, wave, lane);
    stage_tile64(Bb + k0, ldb, Bs, wave, lane);
    __syncthreads();
#pragma unroll
    for (int kk = 0; kk < 2; kk++) {
      short8 af[4], bfr[4];
#pragma unroll
      for (int i = 0; i < 4; i++) af[i] = frag64(As, wr + i * 16 + lr, kk * 4 + quad);
#pragma unroll
      for (int j = 0; j < 4; j++) bfr[j] = frag64(Bs, wc + j * 16 + lr, kk * 4 + quad);
#pragma unroll
      for (int i = 0; i < 4; i++)
#pragma unroll
        for (int j = 0; j < 4; j++)
          acc[i][j] = __builtin_amdgcn_mfma_f32_16x16x32_bf16(af[i], bfr[j], acc[i][j], 0, 0, 0);
    }
  }
  const float alpha = alphac * (alphap ? alphap[0] : 1.0f);
  const long cb = (long)blockIdx.z * sC;
  if (OUT_MODE == 1 || OUT_MODE == 3) {
    // pre-apply alpha + bias in-register (same values/order as before)
#pragma unroll
    for (int i = 0; i < 4; i++)
#pragma unroll
      for (int j = 0; j < 4; j++)
#pragma unroll
        for (int r = 0; r < 4; r++) {
          float v = alpha * acc[i][j][r];
          if (BIAS_MODE == 1) v += bias[n0 + wc + j * 16 + lr];
          if (BIAS_MODE == 2) v += bias[m0 + wr + i * 16 + quad * 4 + r];
          acc[i][j][r] = v;
        }
    float* Cf = (float*)Cv;
#pragma unroll
    for (int pass = 0; pass < 2; pass++) {
      __syncthreads();
      if ((wr >> 6) == pass) {
#pragma unroll
        for (int i = 0; i < 4; i++)
#pragma unroll
          for (int j = 0; j < 4; j++)
#pragma unroll
            for (int r = 0; r < 4; r++)
              scr[(i * 16 + quad * 4 + r) * 132 + wc + j * 16 + lr] = acc[i][j][r];
      }
      __syncthreads();
      const int rrow = tid >> 2;          // 0..63
      const int cg = (tid & 3) << 5;      // col group of 32
      const long m = m0 + pass * 64 + rrow;
      const float* srow = scr + rrow * 132 + cg;
      const long off = cb + m * (long)ldc + n0 + cg;
#pragma unroll
      for (int k = 0; k < 8; k++) {
        float4 v = *(const float4*)(srow + k * 4);
        if (OUT_MODE == 3) {
          float4 res = *(const float4*)(resid + off + k * 4);
          v.x += res.x; v.y += res.y; v.z += res.z; v.w += res.w;
        } else if (BETA_ACC) {
          float4 res = *(const float4*)(Cf + off + k * 4);
          v.x += res.x; v.y += res.y; v.z += res.z; v.w += res.w;
        }
        *(float4*)(Cf + off + k * 4) = v;
      }
    }
  } else {
#pragma unroll
    for (int i = 0; i < 4; i++) {
#pragma unroll
      for (int r = 0; r < 4; r++) {
        long m = m0 + wr + i * 16 + quad * 4 + r;
        float bm = (BIAS_MODE == 2) ? bias[m] : 0.0f;
#pragma unroll
        for (int j = 0; j < 4; j++) {
          long n = n0 + wc + j * 16 + lr;
          float v = alpha * acc[i][j][r];
          if (BIAS_MODE == 1) v += bias[n];
          if (BIAS_MODE == 2) v += bm;
          ((u16*)Cv)[cb + m * (long)ldc + n] = f2b(v);
        }
      }
    }
  }
}

// ---------------- split-K2 GEMM for S (latency-sensitive) ----------------------------
__global__ __launch_bounds__(512)
void gemm_s_sk2(const u16* __restrict__ A, long sA, int lda,
                const u16* __restrict__ Bm, long sB, int ldb,
                float* __restrict__ C, long sC, int ldc,
                float alpha, int K) {
  __shared__ __align__(16) u16 smem[32768];  // 64 KB
  float* scr = (float*)smem;                 // combine + epilogue scratch
  const int tid = threadIdx.x;
  const int h = tid >> 8;               // k-half
  const long m0 = (long)blockIdx.x * 128;
  const long n0 = (long)blockIdx.y * 128;
  const int Kh = K >> 1;
  const u16* Ab = A + (long)blockIdx.z * sA + m0 * lda + (long)h * Kh;
  const u16* Bb = Bm + (long)blockIdx.z * sB + n0 * ldb + (long)h * Kh;
  u16* AsH = smem + h * 8192;
  u16* BsH = smem + 16384 + h * 8192;
  const int wave = tid >> 6;            // 0..7
  const int w4 = wave & 3;              // wave within half
  const int q = wave & 3;               // output quadrant (shared between halves)
  const int lane = tid & 63;
  const int wr = (q >> 1) << 6;
  const int wc = (q & 1) << 6;
  const int quad = lane >> 4;
  const int lr = lane & 15;
  floatx4 acc[4][4] = {};
  for (int k0 = 0; k0 < Kh; k0 += 64) {
    __syncthreads();
    stage_tile64(Ab + k0, lda, AsH, w4, lane);
    stage_tile64(Bb + k0, ldb, BsH, w4, lane);
    __syncthreads();
#pragma unroll
    for (int kk = 0; kk < 2; kk++) {
      short8 af[4], bfr[4];
#pragma unroll
      for (int i = 0; i < 4; i++) af[i] = frag64(AsH, wr + i * 16 + lr, kk * 4 + quad);
#pragma unroll
      for (int j = 0; j < 4; j++) bfr[j] = frag64(BsH, wc + j * 16 + lr, kk * 4 + quad);
#pragma unroll
      for (int i = 0; i < 4; i++)
#pragma unroll
        for (int j = 0; j < 4; j++)
          acc[i][j] = __builtin_amdgcn_mfma_f32_16x16x32_bf16(af[i], bfr[j], acc[i][j], 0, 0, 0);
    }
  }
  __syncthreads();
#pragma unroll
  for (int pass = 0; pass < 2; pass++) {
    if (h == 1 && (q >> 1) == pass) {
#pragma unroll
      for (int i = 0; i < 4; i++)
#pragma unroll
        for (int j = 0; j < 4; j++)
          *(floatx4*)&scr[(q & 1) * 4096 + (j * 16 + lr) * 64 +
                          (((i * 16 + quad * 4)) ^ ((lr & 7) << 2))] = acc[i][j];
    }
    __syncthreads();
    if (h == 0 && (q >> 1) == pass) {
#pragma unroll
      for (int i = 0; i < 4; i++)
#pragma unroll
        for (int j = 0; j < 4; j++)
          acc[i][j] += *(const floatx4*)&scr[(q & 1) * 4096 + (j * 16 + lr) * 64 +
                                             (((i * 16 + quad * 4)) ^ ((lr & 7) << 2))];
    }
    __syncthreads();
  }
  // coalesced epilogue: h==0 waves stage alpha*acc into [64][132] LDS per 64-row
  // half; all 512 threads store float4 over contiguous 512B rows.
  if (h == 0) {
#pragma unroll
    for (int i = 0; i < 4; i++)
#pragma unroll
      for (int j = 0; j < 4; j++)
#pragma unroll
        for (int r = 0; r < 4; r++)
          acc[i][j][r] *= alpha;
  }
  const long cb = (long)blockIdx.z * sC;
#pragma unroll
  for (int pass = 0; pass < 2; pass++) {
    __syncthreads();
    if (h == 0 && (wr >> 6) == pass) {
#pragma unroll
      for (int i = 0; i < 4; i++)
#pragma unroll
        for (int j = 0; j < 4; j++)
#pragma unroll
          for (int r = 0; r < 4; r++)
            scr[(i * 16 + quad * 4 + r) * 132 + wc + j * 16 + lr] = acc[i][j][r];
    }
    __syncthreads();
    const int rrow = tid >> 3;          // 0..63
    const int cg = (tid & 7) << 4;      // col group of 16
    const long m = m0 + pass * 64 + rrow;
    const float* srow = scr + rrow * 132 + cg;
    const long off = cb + m * (long)ldc + n0 + cg;
#pragma unroll
    for (int k = 0; k < 4; k++)
      *(float4*)(C + off + k * 4) = *(const float4*)(srow + k * 4);
  }
}

// ---------------- small vecs + folded softmax3 ---------------------------------------
__global__ __launch_bounds__(256)
void smallvecs_kernel(const float* __restrict__ Wq, const float* __restrict__ Wk,
                      const float* __restrict__ bq, const float* __restrict__ bk,
                      const float* __restrict__ lam,
                      float* __restrict__ hvec, float* __restrict__ uvec,
                      float* __restrict__ w) {
  const int row = blockIdx.x * 4 + (threadIdx.x >> 6);
  const int lane = threadIdx.x & 63;
  if (row == 1793) {
    if (lane == 0) {
      float a = lam[0], b = lam[1], c = lam[2];
      float m = fmaxf(a, fmaxf(b, c));
      float ea = __expf(a - m), eb = __expf(b - m), ec = __expf(c - m);
      float s = ea + eb + ec;
      w[0] = ea / s; w[1] = eb / s; w[2] = ec / s;
    }
    return;
  }
  if (row > 1792) return;
  const float* src; const float* vec; float* dst;
  if (row < 1024) { src = Wq + (long)row * 1024; vec = bk; dst = hvec + row; }
  else if (row < 1792) { src = Wk + (long)(row - 1024) * 1024; vec = bq; dst = uvec + (row - 1024); }
  else { src = bk; vec = bq; dst = uvec + 768; }
  float s = 0.f;
#pragma unroll
  for (int h = 0; h < 4; h++) {
    float4 a = *(const float4*)(src + h * 256 + lane * 4);
    float4 b = *(const float4*)(vec + h * 256 + lane * 4);
    s += a.x * b.x + a.y * b.y + a.z * b.z + a.w * b.w;
  }
#pragma unroll
  for (int o = 32; o > 0; o >>= 1) s += __shfl_xor(s, o);
  if (lane == 0) *dst = s;
}

// ---------------- bkq[b,l] = 0.03125 * (tt16[b,l,:].uvec + beta0) --------------------
__global__ __launch_bounds__(256)
void bkq_kernel(const u16* __restrict__ tt, const float* __restrict__ uvec,
                float* __restrict__ bkq) {
  const long row = (long)blockIdx.x * 4 + (threadIdx.x >> 6);  // [0, 8192)
  const int lane = threadIdx.x & 63;
  const u16* tr = tt + row * 768;
  float s = 0.f;
#pragma unroll
  for (int h = 0; h < 3; h++) {
    uint2 kv = *(const uint2*)(tr + h * 256 + lane * 4);
    const u16* ku = (const u16*)&kv;
    float4 b = *(const float4*)(uvec + h * 256 + lane * 4);
    s += b2f(ku[0]) * b.x + b2f(ku[1]) * b.y + b2f(ku[2]) * b.z + b2f(ku[3]) * b.w;
  }
#pragma unroll
  for (int o = 32; o > 0; o >>= 1) s += __shfl_xor(s, o);
  if (lane == 0) bkq[row] = 0.03125f * (s + uvec[768]);
}

// ---------------- softmax + weighted fp32 accumulate (no intermediate bf16) ----------
__device__ __forceinline__ void sm_accum(float4 a0, float4 a1, float w,
                                         float& o0, float& o1, float& o2, float& o3,
                                         float& o4, float& o5, float& o6, float& o7) {
  float m = fmaxf(fmaxf(fmaxf(a0.x, a0.y), fmaxf(a0.z, a0.w)),
                  fmaxf(fmaxf(a1.x, a1.y), fmaxf(a1.z, a1.w)));
#pragma unroll
  for (int o = 32; o > 0; o >>= 1) m = fmaxf(m, __shfl_xor(m, o));
  float e0 = __expf(a0.x - m), e1 = __expf(a0.y - m), e2 = __expf(a0.z - m), e3 = __expf(a0.w - m);
  float e4 = __expf(a1.x - m), e5 = __expf(a1.y - m), e6 = __expf(a1.z - m), e7 = __expf(a1.w - m);
  float s = ((e0 + e1) + (e2 + e3)) + ((e4 + e5) + (e6 + e7));
#pragma unroll
  for (int o = 32; o > 0; o >>= 1) s += __shfl_xor(s, o);
  const float inv = w / s;
  o0 += e0 * inv; o1 += e1 * inv; o2 += e2 * inv; o3 += e3 * inv;
  o4 += e4 * inv; o5 += e5 * inv; o6 += e6 * inv; o7 += e7 * inv;
}

// ---------------- fused 25-tap 2D pool + 3x softmax -> SINGLE weighted P -------------
__global__ __launch_bounds__(256)
void pool_sm(const float* __restrict__ S1, const float* __restrict__ bkq,
             u16* __restrict__ P, const float* __restrict__ wts) {
  const int row = blockIdx.x * 4 + (threadIdx.x >> 6);
  const int lane = threadIdx.x & 63;
  const int bloc = row / 2304;
  const int nn = row - bloc * 2304;
  const int x = nn % 48;
  const int y = nn / 48;
  float4 c0 = {0.f, 0.f, 0.f, 0.f}, c1 = {0.f, 0.f, 0.f, 0.f};
  float4 a3x = {0.f, 0.f, 0.f, 0.f}, a3y = {0.f, 0.f, 0.f, 0.f};
  float4 a5x = {0.f, 0.f, 0.f, 0.f}, a5y = {0.f, 0.f, 0.f, 0.f};
#pragma unroll
  for (int dy = -2; dy <= 2; dy++) {
    int yy = y + dy;
    if (yy < 0 || yy >= 48) continue;
    float4 h5x = {0.f, 0.f, 0.f, 0.f}, h5y = {0.f, 0.f, 0.f, 0.f};
    float4 h3x = {0.f, 0.f, 0.f, 0.f}, h3y = {0.f, 0.f, 0.f, 0.f};
#pragma unroll
    for (int dx = -2; dx <= 2; dx++) {
      int xx = x + dx;
      if (xx < 0 || xx >= 48) continue;
      const float* r = S1 + (long)(row + dy * 48 + dx) * 512;
      float4 v0 = *(const float4*)(r + lane * 4);
      float4 v1 = *(const float4*)(r + 256 + lane * 4);
      h5x.x += v0.x; h5x.y += v0.y; h5x.z += v0.z; h5x.w += v0.w;
      h5y.x += v1.x; h5y.y += v1.y; h5y.z += v1.z; h5y.w += v1.w;
      if (dx >= -1 && dx <= 1) {
        h3x.x += v0.x; h3x.y += v0.y; h3x.z += v0.z; h3x.w += v0.w;
        h3y.x += v1.x; h3y.y += v1.y; h3y.z += v1.z; h3y.w += v1.w;
      }
      if (dx == 0 && dy == 0) { c0 = v0; c1 = v1; }
    }
    a5x.x += h5x.x; a5x.y += h5x.y; a5x.z += h5x.z; a5x.w += h5x.w;
    a5y.x += h5y.x; a5y.y += h5y.y; a5y.z += h5y.z; a5y.w += h5y.w;
    if (dy >= -1 && dy <= 1) {
      a3x.x += h3x.x; a3x.y += h3x.y; a3x.z += h3x.z; a3x.w += h3x.w;
      a3y.x += h3y.x; a3y.y += h3y.y; a3y.z += h3y.z; a3y.w += h3y.w;
    }
  }
  const float* bk = bkq + (long)bloc * 512;
  float4 q0 = *(const float4*)(bk + lane * 4);
  float4 q1v = *(const float4*)(bk + 256 + lane * 4);
  float o0 = 0.f, o1 = 0.f, o2 = 0.f, o3 = 0.f, o4 = 0.f, o5 = 0.f, o6 = 0.f, o7 = 0.f;
  // scale 1: raw center + bkq
  c0.x += q0.x;  c0.y += q0.y;  c0.z += q0.z;  c0.w += q0.w;
  c1.x += q1v.x; c1.y += q1v.y; c1.z += q1v.z; c1.w += q1v.w;
  sm_accum(c0, c1, wts[0], o0, o1, o2, o3, o4, o5, o6, o7);
  // scale 3
  const float ik3 = 1.0f / 9.0f;
  a3x.x = a3x.x * ik3 + q0.x;  a3x.y = a3x.y * ik3 + q0.y;
  a3x.z = a3x.z * ik3 + q0.z;  a3x.w = a3x.w * ik3 + q0.w;
  a3y.x = a3y.x * ik3 + q1v.x; a3y.y = a3y.y * ik3 + q1v.y;
  a3y.z = a3y.z * ik3 + q1v.z; a3y.w = a3y.w * ik3 + q1v.w;
  sm_accum(a3x, a3y, wts[1], o0, o1, o2, o3, o4, o5, o6, o7);
  // scale 5
  const float ik5 = 1.0f / 25.0f;
  a5x.x = a5x.x * ik5 + q0.x;  a5x.y = a5x.y * ik5 + q0.y;
  a5x.z = a5x.z * ik5 + q0.z;  a5x.w = a5x.w * ik5 + q0.w;
  a5y.x = a5y.x * ik5 + q1v.x; a5y.y = a5y.y * ik5 + q1v.y;
  a5y.z = a5y.z * ik5 + q1v.z; a5y.w = a5y.w * ik5 + q1v.w;
  sm_accum(a5x, a5y, wts[2], o0, o1, o2, o3, o4, o5, o6, o7);
  // single bf16 write
  union { u16 u[4]; uint2 v; } pk;
  u16* pr = P + (long)row * 512;
  pk.u[0] = f2b(o0); pk.u[1] = f2b(o1); pk.u[2] = f2b(o2); pk.u[3] = f2b(o3);
  *(uint2*)(pr + lane * 4) = pk.v;
  pk.u[0] = f2b(o4); pk.u[1] = f2b(o5); pk.u[2] = f2b(o6); pk.u[3] = f2b(o7);
  *(uint2*)(pr + 256 + lane * 4) = pk.v;
}

extern "C" void kernel_launch(void* const* d_in, const int* in_sizes, int n_in,
                              void* d_out, int out_size, void* d_ws, size_t ws_size,
                              hipStream_t stream) {
  const float* v_feat = (const float*)d_in[0];
  const float* t_tok  = (const float*)d_in[1];
  const float* Wq  = (const float*)d_in[2];
  const float* bq  = (const float*)d_in[3];
  const float* Wk  = (const float*)d_in[4];
  const float* bk  = (const float*)d_in[5];
  const float* Wv  = (const float*)d_in[6];
  const float* bv  = (const float*)d_in[7];
  const float* lam = (const float*)d_in[8];

  // Persistent region: 40.4 MB. Chunked region: NB batches x 11.8 MB.
  char* const wsb = (char*)d_ws;
  float* wts  = (float*)(wsb);                  // 256 B
  u16* Wq16   = (u16*)(wsb + 256);              // 2 MB
  u16* Wk16   = (u16*)(wsb + 2097408);          // 1.5 MB
  u16* WvT    = (u16*)(wsb + 3670272);          // 1.5 MB
  u16* GT     = (u16*)(wsb + 5243136);          // (1024, 768) bf16, 1.5 MB
  float* hvec = (float*)(wsb + 6816000);        // 4 KB
  float* uvec = (float*)(wsb + 6820096);        // 769 floats (+pad)
  float* bkq  = (float*)(wsb + 6824192);        // (B, L) fp32, 32 KB
  u16* WkqT   = (u16*)(wsb + 6856960);          // (B*L, C) bf16, 16.8 MB
  u16* vtxtT  = (u16*)(wsb + 23634176);         // (B, C, L) bf16, 16.8 MB
  const long chunkBase = 40411392;
  char* const chunk = wsb + chunkBase;
  u16* tt16   = (u16*)chunk;                    // 12.6 MB (pre-loop only)

  int NB = 4;
  if (ws_size >= chunkBase + 16L * 11796480) NB = 16;
  else if (ws_size >= chunkBase + 8L * 11796480) NB = 8;
  const long vfB = (long)NB * 2304 * 1024 * 2;  // vflat bytes
  const long sB_ = (long)NB * 2304 * 512 * 4;   // S bytes
  u16* vflatN = (u16*)chunk;
  float* SN   = (float*)(chunk + vfB);
  u16* Psum   = (u16*)(chunk + vfB + sB_);

  float* out0 = (float*)d_out;
  const long CN = 1024L * 2304;

  // merged cast Wq|Wk|t_tok + smallvecs (incl. folded softmax3)
  cast3_kernel<<<3968, 256, 0, stream>>>(Wq, Wk, t_tok, Wq16, Wk16, tt16);
  transpose_f32<<<dim3(12, 16, 1), 256, 0, stream>>>(Wv, WvT, 768, 1024, 0, 0);
  smallvecs_kernel<<<449, 256, 0, stream>>>(Wq, Wk, bq, bk, lam, hvec, uvec, wts);

  // GT(ci,t) = sum_co Wq(ci,co) * Wk(t,co)   : (1024, 768), K=1024
  gemm_nt<0, 0, false><<<dim3(8, 6, 1), 256, 0, stream>>>(
      Wq16, 0, 1024, Wk16, 0, 1024, GT, 0, 768, nullptr, nullptr, nullptr, 1.0f, 1024);
  // WkqT(l,ci) = sum_t tt16(l,t) * GT(ci,t) + h(ci)  : (8192, 1024), K=768
  gemm_nt<1, 0, false><<<dim3(64, 8, 1), 256, 0, stream>>>(
      tt16, 0, 768, GT, 0, 768, WkqT, 0, 1024, hvec, nullptr, nullptr, 1.0f, 768);
  // v_txtT(b) = Wv^T @ t_tok(b)^T + bv (per-m) : (1024,512) per batch, K=768
  gemm_nt<2, 0, false><<<dim3(8, 4, 16), 256, 0, stream>>>(
      WvT, 0, 768, tt16, 512L * 768, 768, vtxtT, 1024L * 512, 512, bv, nullptr, nullptr, 1.0f, 768);
  // bkq[b,l] = scale * (tt16[b,l,:].u + beta0)
  bkq_kernel<<<2048, 256, 0, stream>>>(tt16, uvec, bkq);

  for (int b0 = 0; b0 < 16; b0 += NB) {
    // vflat = transpose(v_feat NB-batch chunk) as bf16: (NB*N, C)
    transpose_f32<<<dim3(16, 36, NB), 256, 0, stream>>>(
        v_feat + b0 * CN, vflatN, 1024, 2304, CN, 2304L * 1024);
    // S = (vflat @ WkqT_b^T) / 32  (fp32, per batch), split-K2
    gemm_s_sk2<<<dim3(18, 4, NB), 512, 0, stream>>>(
        vflatN, 2304L * 1024, 1024, WkqT + (long)b0 * (512L * 1024), 512L * 1024, 1024,
        SN, 2304L * 512, 512, 0.03125f, 1024);
    // fused 25-tap pool + 3 softmaxes -> single weighted Psum (K=512 for PV)
    pool_sm<<<576 * NB, 256, 0, stream>>>(SN, bkq + (long)b0 * 512, Psum, wts);
    // out^T: out(c,n) = sum_l vtxtT(c,l) * Psum(n,l) + v_feat(c,n)
    gemm_nt<0, 3, false><<<dim3(8, 18, NB), 256, 0, stream>>>(
        vtxtT + (long)b0 * (1024L * 512), 1024L * 512, 512, Psum, 2304L * 512, 512,
        out0 + b0 * CN, CN, 2304, nullptr, v_feat + b0 * CN, nullptr, 1.0f, 512);
  }

  // out1 = t_tok (raw fp32 copy)
  hipMemcpyAsync((void*)(out0 + 37748736L), (const void*)t_tok, 25165824L,
                 hipMemcpyDeviceToDevice, stream);
}

// Round 11
// 674.913 us; speedup vs baseline: 1.0317x; 1.0317x over previous
//
#include <hip/hip_runtime.h>

typedef unsigned short u16;
typedef short short8 __attribute__((ext_vector_type(8)));
typedef float floatx4 __attribute__((ext_vector_type(4)));

__device__ __forceinline__ float b2f(u16 h) {
  union { unsigned int u; float f; } z;
  z.u = ((unsigned int)h) << 16;
  return z.f;
}
__device__ __forceinline__ u16 f2b(float f) {
  union { float f; unsigned int u; } z;
  z.f = f;
  unsigned int u = z.u;
  unsigned int r = (u + 0x7fffu + ((u >> 16) & 1u)) >> 16;
  return (u16)r;
}

// ---- global_load_lds staging of a 128x64 bf16 tile (16 KB), XOR-swizzled ----------
__device__ __forceinline__ void stage_tile64(const u16* __restrict__ gsrc, int lda,
                                             u16* lds, int wave, int lane) {
#pragma unroll
  for (int i = 0; i < 4; i++) {
    const int s = wave * 256 + i * 64 + lane;
    const int row = s >> 3;
    const int c8 = (s & 7) ^ (row & 7);
    const u16* g = gsrc + (long)row * lda + (c8 << 3);
    u16* l = lds + (wave * 256 + i * 64) * 8;  // wave-uniform
    __builtin_amdgcn_global_load_lds(
        (const __attribute__((address_space(1))) unsigned int*)g,
        (__attribute__((address_space(3))) unsigned int*)l, 16, 0, 0);
  }
}
// swizzled 16B fragment read: row in [0,128), slot in [0,8)
__device__ __forceinline__ short8 frag64(const u16* lds, int row, int slot) {
  return *(const short8*)(lds + (row << 6) + ((slot ^ (row & 7)) << 3));
}

// ---------------- merged cast fp32 -> bf16 for Wq | Wk | t_tok -----------------------
__global__ __launch_bounds__(256)
void cast3_kernel(const float* __restrict__ Wq, const float* __restrict__ Wk,
                  const float* __restrict__ tt, u16* __restrict__ Wq16,
                  u16* __restrict__ Wk16, u16* __restrict__ tt16) {
  const int blk = blockIdx.x;
  const float* src; u16* dst; long base;
  if (blk < 512) { src = Wq; dst = Wq16; base = (long)blk; }
  else if (blk < 896) { src = Wk; dst = Wk16; base = (long)(blk - 512); }
  else { src = tt; dst = tt16; base = (long)(blk - 896); }
  const long i = (base * 256 + threadIdx.x) * 8;
  float4 v0 = *(const float4*)(src + i);
  float4 v1 = *(const float4*)(src + i + 4);
  u16 r[8] __attribute__((aligned(16)));
  r[0] = f2b(v0.x); r[1] = f2b(v0.y); r[2] = f2b(v0.z); r[3] = f2b(v0.w);
  r[4] = f2b(v1.x); r[5] = f2b(v1.y); r[6] = f2b(v1.z); r[7] = f2b(v1.w);
  *(uint4*)(dst + i) = *(const uint4*)r;
}

// ---------------- transpose fp32 src (b,R,Cc) -> bf16 dst (b,Cc,R) ------------------
__global__ __launch_bounds__(256)
void transpose_f32(const float* __restrict__ src, u16* __restrict__ dst,
                   int R, int Cc, long sSrc, long sDst) {
  __shared__ u16 t[64][66];
  const int tid = threadIdx.x;
  const long r0 = (long)blockIdx.x << 6;
  const long c0 = (long)blockIdx.y << 6;
  const float* s = src + (long)blockIdx.z * sSrc;
  u16* d = dst + (long)blockIdx.z * sDst;
  const int rr = tid >> 2;
  const int cb = (tid & 3) << 2;  // 0,4,8,12
#pragma unroll
  for (int h = 0; h < 4; h++) {
    int cc = cb + h * 16;
    float4 v = *(const float4*)(s + (r0 + rr) * Cc + c0 + cc);
    t[rr][cc + 0] = f2b(v.x); t[rr][cc + 1] = f2b(v.y);
    t[rr][cc + 2] = f2b(v.z); t[rr][cc + 3] = f2b(v.w);
  }
  __syncthreads();
  const int cr = tid >> 2;
  const int nb0 = (tid & 3) << 3;
#pragma unroll
  for (int h = 0; h < 2; h++) {
    int rb = nb0 + h * 32;
    u16 res[8] __attribute__((aligned(16)));
#pragma unroll
    for (int j = 0; j < 8; j++) res[j] = t[rb + j][cr];
    *(uint4*)(d + (c0 + cr) * R + r0 + rb) = *(const uint4*)res;
  }
}

// ---------------- GEMM: C = alpha * A(row-major MxK) * B^T (B is NxK row-major) ------
// BK=64, global_load_lds staging, XOR-swizzled LDS. K must be a multiple of 64.
// OUT_MODE: 0 bf16 (direct store); 1 fp32; 3 fp32 + resid add. Modes 1/3 use an
// LDS-staged epilogue: [64][128] scratch with col^((row&7)<<2) swizzle ->
// write 2-way (free), read conflict-free, 512B-contiguous global rows.
template <int BIAS_MODE, int OUT_MODE, bool BETA_ACC>
__global__ __launch_bounds__(256)
void gemm_nt(const u16* __restrict__ A, long sA, int lda,
             const u16* __restrict__ Bm, long sB, int ldb,
             void* __restrict__ Cv, long sC, int ldc,
             const float* __restrict__ bias, const float* __restrict__ resid,
             const float* __restrict__ alphap, float alphac, int K) {
  __shared__ __align__(16) char smem[32768];
  u16* As = (u16*)smem;
  u16* Bs = (u16*)(smem + 16384);
  float* scr = (float*)smem;  // epilogue scratch [64][128] (aliases As/Bs, dead then)
  const int tid = threadIdx.x;
  const long m0 = (long)blockIdx.x * 128;
  const long n0 = (long)blockIdx.y * 128;
  const u16* Ab = A + (long)blockIdx.z * sA + m0 * lda;
  const u16* Bb = Bm + (long)blockIdx.z * sB + n0 * ldb;
  const int wave = tid >> 6;
  const int lane = tid & 63;
  const int wr = (wave >> 1) << 6;
  const int wc = (wave & 1) << 6;
  const int quad = lane >> 4;
  const int lr = lane & 15;
  floatx4 acc[4][4] = {};
  for (int k0 = 0; k0 < K; k0 += 64) {
    __syncthreads();
    stage_tile64(Ab + k0, lda, As, wave, lane);
    stage_tile64(Bb + k0, ldb, Bs, wave, lane);
    __syncthreads();
#pragma unroll
    for (int kk = 0; kk < 2; kk++) {
      short8 af[4], bfr[4];
#pragma unroll
      for (int i = 0; i < 4; i++) af[i] = frag64(As, wr + i * 16 + lr, kk * 4 + quad);
#pragma unroll
      for (int j = 0; j < 4; j++) bfr[j] = frag64(Bs, wc + j * 16 + lr, kk * 4 + quad);
#pragma unroll
      for (int i = 0; i < 4; i++)
#pragma unroll
        for (int j = 0; j < 4; j++)
          acc[i][j] = __builtin_amdgcn_mfma_f32_16x16x32_bf16(af[i], bfr[j], acc[i][j], 0, 0, 0);
    }
  }
  const float alpha = alphac * (alphap ? alphap[0] : 1.0f);
  const long cb = (long)blockIdx.z * sC;
  if (OUT_MODE == 1 || OUT_MODE == 3) {
    // pre-apply alpha + bias in-register (same values/order as before)
#pragma unroll
    for (int i = 0; i < 4; i++)
#pragma unroll
      for (int j = 0; j < 4; j++)
#pragma unroll
        for (int r = 0; r < 4; r++) {
          float v = alpha * acc[i][j][r];
          if (BIAS_MODE == 1) v += bias[n0 + wc + j * 16 + lr];
          if (BIAS_MODE == 2) v += bias[m0 + wr + i * 16 + quad * 4 + r];
          acc[i][j][r] = v;
        }
    float* Cf = (float*)Cv;
#pragma unroll
    for (int pass = 0; pass < 2; pass++) {
      __syncthreads();
      if ((wr >> 6) == pass) {
#pragma unroll
        for (int i = 0; i < 4; i++) {
#pragma unroll
          for (int r = 0; r < 4; r++) {
            const int row = i * 16 + quad * 4 + r;
            const int sw = (row & 7) << 2;
#pragma unroll
            for (int j = 0; j < 4; j++)
              scr[row * 128 + ((wc + j * 16 + lr) ^ sw)] = acc[i][j][r];
          }
        }
      }
      __syncthreads();
      const int l32 = tid & 31;
      const int rbase = tid >> 5;  // 0..7
#pragma unroll
      for (int c = 0; c < 8; c++) {
        const int row = c * 8 + rbase;
        const int col = l32 * 4;
        const float* sp = scr + row * 128 + (col ^ ((row & 7) << 2));
        float4 v = *(const float4*)sp;
        const long off = cb + (m0 + pass * 64 + row) * (long)ldc + n0 + col;
        if (OUT_MODE == 3) {
          float4 res = *(const float4*)(resid + off);
          v.x += res.x; v.y += res.y; v.z += res.z; v.w += res.w;
        } else if (BETA_ACC) {
          float4 res = *(const float4*)(Cf + off);
          v.x += res.x; v.y += res.y; v.z += res.z; v.w += res.w;
        }
        *(float4*)(Cf + off) = v;
      }
    }
  } else {
#pragma unroll
    for (int i = 0; i < 4; i++) {
#pragma unroll
      for (int r = 0; r < 4; r++) {
        long m = m0 + wr + i * 16 + quad * 4 + r;
        float bm = (BIAS_MODE == 2) ? bias[m] : 0.0f;
#pragma unroll
        for (int j = 0; j < 4; j++) {
          long n = n0 + wc + j * 16 + lr;
          float v = alpha * acc[i][j][r];
          if (BIAS_MODE == 1) v += bias[n];
          if (BIAS_MODE == 2) v += bm;
          ((u16*)Cv)[cb + m * (long)ldc + n] = f2b(v);
        }
      }
    }
  }
}

// ---------------- split-K2 GEMM for S (latency-sensitive) ----------------------------
__global__ __launch_bounds__(512)
void gemm_s_sk2(const u16* __restrict__ A, long sA, int lda,
                const u16* __restrict__ Bm, long sB, int ldb,
                float* __restrict__ C, long sC, int ldc,
                float alpha, int K) {
  __shared__ __align__(16) u16 smem[32768];  // 64 KB
  float* scr = (float*)smem;                 // combine + epilogue scratch
  const int tid = threadIdx.x;
  const int h = tid >> 8;               // k-half
  const long m0 = (long)blockIdx.x * 128;
  const long n0 = (long)blockIdx.y * 128;
  const int Kh = K >> 1;
  const u16* Ab = A + (long)blockIdx.z * sA + m0 * lda + (long)h * Kh;
  const u16* Bb = Bm + (long)blockIdx.z * sB + n0 * ldb + (long)h * Kh;
  u16* AsH = smem + h * 8192;
  u16* BsH = smem + 16384 + h * 8192;
  const int wave = tid >> 6;            // 0..7
  const int w4 = wave & 3;              // wave within half
  const int q = wave & 3;               // output quadrant (shared between halves)
  const int lane = tid & 63;
  const int wr = (q >> 1) << 6;
  const int wc = (q & 1) << 6;
  const int quad = lane >> 4;
  const int lr = lane & 15;
  floatx4 acc[4][4] = {};
  for (int k0 = 0; k0 < Kh; k0 += 64) {
    __syncthreads();
    stage_tile64(Ab + k0, lda, AsH, w4, lane);
    stage_tile64(Bb + k0, ldb, BsH, w4, lane);
    __syncthreads();
#pragma unroll
    for (int kk = 0; kk < 2; kk++) {
      short8 af[4], bfr[4];
#pragma unroll
      for (int i = 0; i < 4; i++) af[i] = frag64(AsH, wr + i * 16 + lr, kk * 4 + quad);
#pragma unroll
      for (int j = 0; j < 4; j++) bfr[j] = frag64(BsH, wc + j * 16 + lr, kk * 4 + quad);
#pragma unroll
      for (int i = 0; i < 4; i++)
#pragma unroll
        for (int j = 0; j < 4; j++)
          acc[i][j] = __builtin_amdgcn_mfma_f32_16x16x32_bf16(af[i], bfr[j], acc[i][j], 0, 0, 0);
    }
  }
  __syncthreads();
#pragma unroll
  for (int pass = 0; pass < 2; pass++) {
    if (h == 1 && (q >> 1) == pass) {
#pragma unroll
      for (int i = 0; i < 4; i++)
#pragma unroll
        for (int j = 0; j < 4; j++)
          *(floatx4*)&scr[(q & 1) * 4096 + (j * 16 + lr) * 64 +
                          (((i * 16 + quad * 4)) ^ ((lr & 7) << 2))] = acc[i][j];
    }
    __syncthreads();
    if (h == 0 && (q >> 1) == pass) {
#pragma unroll
      for (int i = 0; i < 4; i++)
#pragma unroll
        for (int j = 0; j < 4; j++)
          acc[i][j] += *(const floatx4*)&scr[(q & 1) * 4096 + (j * 16 + lr) * 64 +
                                             (((i * 16 + quad * 4)) ^ ((lr & 7) << 2))];
    }
    __syncthreads();
  }
  // coalesced epilogue: h==0 waves stage alpha*acc into swizzled [64][128] LDS per
  // 64-row half; all 512 threads store float4 over contiguous 512B rows.
  if (h == 0) {
#pragma unroll
    for (int i = 0; i < 4; i++)
#pragma unroll
      for (int j = 0; j < 4; j++)
#pragma unroll
        for (int r = 0; r < 4; r++)
          acc[i][j][r] *= alpha;
  }
  const long cb = (long)blockIdx.z * sC;
#pragma unroll
  for (int pass = 0; pass < 2; pass++) {
    __syncthreads();
    if (h == 0 && (wr >> 6) == pass) {
#pragma unroll
      for (int i = 0; i < 4; i++) {
#pragma unroll
        for (int r = 0; r < 4; r++) {
          const int row = i * 16 + quad * 4 + r;
          const int sw = (row & 7) << 2;
#pragma unroll
          for (int j = 0; j < 4; j++)
            scr[row * 128 + ((wc + j * 16 + lr) ^ sw)] = acc[i][j][r];
        }
      }
    }
    __syncthreads();
    const int l32 = tid & 31;
    const int rbase = tid >> 5;  // 0..15
#pragma unroll
    for (int c = 0; c < 4; c++) {
      const int row = c * 16 + rbase;
      const int col = l32 * 4;
      const float* sp = scr + row * 128 + (col ^ ((row & 7) << 2));
      float4 v = *(const float4*)sp;
      const long off = cb + (m0 + pass * 64 + row) * (long)ldc + n0 + col;
      *(float4*)(C + off) = v;
    }
  }
}

// ---------------- small vecs + folded softmax3 ---------------------------------------
__global__ __launch_bounds__(256)
void smallvecs_kernel(const float* __restrict__ Wq, const float* __restrict__ Wk,
                      const float* __restrict__ bq, const float* __restrict__ bk,
                      const float* __restrict__ lam,
                      float* __restrict__ hvec, float* __restrict__ uvec,
                      float* __restrict__ w) {
  const int row = blockIdx.x * 4 + (threadIdx.x >> 6);
  const int lane = threadIdx.x & 63;
  if (row == 1793) {
    if (lane == 0) {
      float a = lam[0], b = lam[1], c = lam[2];
      float m = fmaxf(a, fmaxf(b, c));
      float ea = __expf(a - m), eb = __expf(b - m), ec = __expf(c - m);
      float s = ea + eb + ec;
      w[0] = ea / s; w[1] = eb / s; w[2] = ec / s;
    }
    return;
  }
  if (row > 1792) return;
  const float* src; const float* vec; float* dst;
  if (row < 1024) { src = Wq + (long)row * 1024; vec = bk; dst = hvec + row; }
  else if (row < 1792) { src = Wk + (long)(row - 1024) * 1024; vec = bq; dst = uvec + (row - 1024); }
  else { src = bk; vec = bq; dst = uvec + 768; }
  float s = 0.f;
#pragma unroll
  for (int h = 0; h < 4; h++) {
    float4 a = *(const float4*)(src + h * 256 + lane * 4);
    float4 b = *(const float4*)(vec + h * 256 + lane * 4);
    s += a.x * b.x + a.y * b.y + a.z * b.z + a.w * b.w;
  }
#pragma unroll
  for (int o = 32; o > 0; o >>= 1) s += __shfl_xor(s, o);
  if (lane == 0) *dst = s;
}

// ---------------- bkq[b,l] = 0.03125 * (tt16[b,l,:].uvec + beta0) --------------------
__global__ __launch_bounds__(256)
void bkq_kernel(const u16* __restrict__ tt, const float* __restrict__ uvec,
                float* __restrict__ bkq) {
  const long row = (long)blockIdx.x * 4 + (threadIdx.x >> 6);  // [0, 8192)
  const int lane = threadIdx.x & 63;
  const u16* tr = tt + row * 768;
  float s = 0.f;
#pragma unroll
  for (int h = 0; h < 3; h++) {
    uint2 kv = *(const uint2*)(tr + h * 256 + lane * 4);
    const u16* ku = (const u16*)&kv;
    float4 b = *(const float4*)(uvec + h * 256 + lane * 4);
    s += b2f(ku[0]) * b.x + b2f(ku[1]) * b.y + b2f(ku[2]) * b.z + b2f(ku[3]) * b.w;
  }
#pragma unroll
  for (int o = 32; o > 0; o >>= 1) s += __shfl_xor(s, o);
  if (lane == 0) bkq[row] = 0.03125f * (s + uvec[768]);
}

// ---------------- softmax + weighted fp32 accumulate (no intermediate bf16) ----------
__device__ __forceinline__ void sm_accum(float4 a0, float4 a1, float w,
                                         float& o0, float& o1, float& o2, float& o3,
                                         float& o4, float& o5, float& o6, float& o7) {
  float m = fmaxf(fmaxf(fmaxf(a0.x, a0.y), fmaxf(a0.z, a0.w)),
                  fmaxf(fmaxf(a1.x, a1.y), fmaxf(a1.z, a1.w)));
#pragma unroll
  for (int o = 32; o > 0; o >>= 1) m = fmaxf(m, __shfl_xor(m, o));
  float e0 = __expf(a0.x - m), e1 = __expf(a0.y - m), e2 = __expf(a0.z - m), e3 = __expf(a0.w - m);
  float e4 = __expf(a1.x - m), e5 = __expf(a1.y - m), e6 = __expf(a1.z - m), e7 = __expf(a1.w - m);
  float s = ((e0 + e1) + (e2 + e3)) + ((e4 + e5) + (e6 + e7));
#pragma unroll
  for (int o = 32; o > 0; o >>= 1) s += __shfl_xor(s, o);
  const float inv = w / s;
  o0 += e0 * inv; o1 += e1 * inv; o2 += e2 * inv; o3 += e3 * inv;
  o4 += e4 * inv; o5 += e5 * inv; o6 += e6 * inv; o7 += e7 * inv;
}

// ---------------- fused 25-tap 2D pool + 3x softmax -> SINGLE weighted P -------------
__global__ __launch_bounds__(256)
void pool_sm(const float* __restrict__ S1, const float* __restrict__ bkq,
             u16* __restrict__ P, const float* __restrict__ wts) {
  const int row = blockIdx.x * 4 + (threadIdx.x >> 6);
  const int lane = threadIdx.x & 63;
  const int bloc = row / 2304;
  const int nn = row - bloc * 2304;
  const int x = nn % 48;
  const int y = nn / 48;
  float4 c0 = {0.f, 0.f, 0.f, 0.f}, c1 = {0.f, 0.f, 0.f, 0.f};
  float4 a3x = {0.f, 0.f, 0.f, 0.f}, a3y = {0.f, 0.f, 0.f, 0.f};
  float4 a5x = {0.f, 0.f, 0.f, 0.f}, a5y = {0.f, 0.f, 0.f, 0.f};
#pragma unroll
  for (int dy = -2; dy <= 2; dy++) {
    int yy = y + dy;
    if (yy < 0 || yy >= 48) continue;
    float4 h5x = {0.f, 0.f, 0.f, 0.f}, h5y = {0.f, 0.f, 0.f, 0.f};
    float4 h3x = {0.f, 0.f, 0.f, 0.f}, h3y = {0.f, 0.f, 0.f, 0.f};
#pragma unroll
    for (int dx = -2; dx <= 2; dx++) {
      int xx = x + dx;
      if (xx < 0 || xx >= 48) continue;
      const float* r = S1 + (long)(row + dy * 48 + dx) * 512;
      float4 v0 = *(const float4*)(r + lane * 4);
      float4 v1 = *(const float4*)(r + 256 + lane * 4);
      h5x.x += v0.x; h5x.y += v0.y; h5x.z += v0.z; h5x.w += v0.w;
      h5y.x += v1.x; h5y.y += v1.y; h5y.z += v1.z; h5y.w += v1.w;
      if (dx >= -1 && dx <= 1) {
        h3x.x += v0.x; h3x.y += v0.y; h3x.z += v0.z; h3x.w += v0.w;
        h3y.x += v1.x; h3y.y += v1.y; h3y.z += v1.z; h3y.w += v1.w;
      }
      if (dx == 0 && dy == 0) { c0 = v0; c1 = v1; }
    }
    a5x.x += h5x.x; a5x.y += h5x.y; a5x.z += h5x.z; a5x.w += h5x.w;
    a5y.x += h5y.x; a5y.y += h5y.y; a5y.z += h5y.z; a5y.w += h5y.w;
    if (dy >= -1 && dy <= 1) {
      a3x.x += h3x.x; a3x.y += h3x.y; a3x.z += h3x.z; a3x.w += h3x.w;
      a3y.x += h3y.x; a3y.y += h3y.y; a3y.z += h3y.z; a3y.w += h3y.w;
    }
  }
  const float* bk = bkq + (long)bloc * 512;
  float4 q0 = *(const float4*)(bk + lane * 4);
  float4 q1v = *(const float4*)(bk + 256 + lane * 4);
  float o0 = 0.f, o1 = 0.f, o2 = 0.f, o3 = 0.f, o4 = 0.f, o5 = 0.f, o6 = 0.f, o7 = 0.f;
  // scale 1: raw center + bkq
  c0.x += q0.x;  c0.y += q0.y;  c0.z += q0.z;  c0.w += q0.w;
  c1.x += q1v.x; c1.y += q1v.y; c1.z += q1v.z; c1.w += q1v.w;
  sm_accum(c0, c1, wts[0], o0, o1, o2, o3, o4, o5, o6, o7);
  // scale 3
  const float ik3 = 1.0f / 9.0f;
  a3x.x = a3x.x * ik3 + q0.x;  a3x.y = a3x.y * ik3 + q0.y;
  a3x.z = a3x.z * ik3 + q0.z;  a3x.w = a3x.w * ik3 + q0.w;
  a3y.x = a3y.x * ik3 + q1v.x; a3y.y = a3y.y * ik3 + q1v.y;
  a3y.z = a3y.z * ik3 + q1v.z; a3y.w = a3y.w * ik3 + q1v.w;
  sm_accum(a3x, a3y, wts[1], o0, o1, o2, o3, o4, o5, o6, o7);
  // scale 5
  const float ik5 = 1.0f / 25.0f;
  a5x.x = a5x.x * ik5 + q0.x;  a5x.y = a5x.y * ik5 + q0.y;
  a5x.z = a5x.z * ik5 + q0.z;  a5x.w = a5x.w * ik5 + q0.w;
  a5y.x = a5y.x * ik5 + q1v.x; a5y.y = a5y.y * ik5 + q1v.y;
  a5y.z = a5y.z * ik5 + q1v.z; a5y.w = a5y.w * ik5 + q1v.w;
  sm_accum(a5x, a5y, wts[2], o0, o1, o2, o3, o4, o5, o6, o7);
  // single bf16 write
  union { u16 u[4]; uint2 v; } pk;
  u16* pr = P + (long)row * 512;
  pk.u[0] = f2b(o0); pk.u[1] = f2b(o1); pk.u[2] = f2b(o2); pk.u[3] = f2b(o3);
  *(uint2*)(pr + lane * 4) = pk.v;
  pk.u[0] = f2b(o4); pk.u[1] = f2b(o5); pk.u[2] = f2b(o6); pk.u[3] = f2b(o7);
  *(uint2*)(pr + 256 + lane * 4) = pk.v;
}

extern "C" void kernel_launch(void* const* d_in, const int* in_sizes, int n_in,
                              void* d_out, int out_size, void* d_ws, size_t ws_size,
                              hipStream_t stream) {
  const float* v_feat = (const float*)d_in[0];
  const float* t_tok  = (const float*)d_in[1];
  const float* Wq  = (const float*)d_in[2];
  const float* bq  = (const float*)d_in[3];
  const float* Wk  = (const float*)d_in[4];
  const float* bk  = (const float*)d_in[5];
  const float* Wv  = (const float*)d_in[6];
  const float* bv  = (const float*)d_in[7];
  const float* lam = (const float*)d_in[8];

  // Persistent region: 40.4 MB. Chunked region: NB batches x 11.8 MB.
  char* const wsb = (char*)d_ws;
  float* wts  = (float*)(wsb);                  // 256 B
  u16* Wq16   = (u16*)(wsb + 256);              // 2 MB
  u16* Wk16   = (u16*)(wsb + 2097408);          // 1.5 MB
  u16* WvT    = (u16*)(wsb + 3670272);          // 1.5 MB
  u16* GT     = (u16*)(wsb + 5243136);          // (1024, 768) bf16, 1.5 MB
  float* hvec = (float*)(wsb + 6816000);        // 4 KB
  float* uvec = (float*)(wsb + 6820096);        // 769 floats (+pad)
  float* bkq  = (float*)(wsb + 6824192);        // (B, L) fp32, 32 KB
  u16* WkqT   = (u16*)(wsb + 6856960);          // (B*L, C) bf16, 16.8 MB
  u16* vtxtT  = (u16*)(wsb + 23634176);         // (B, C, L) bf16, 16.8 MB
  const long chunkBase = 40411392;
  char* const chunk = wsb + chunkBase;
  u16* tt16   = (u16*)chunk;                    // 12.6 MB (pre-loop only)

  int NB = 4;
  if (ws_size >= chunkBase + 16L * 11796480) NB = 16;
  else if (ws_size >= chunkBase + 8L * 11796480) NB = 8;
  const long vfB = (long)NB * 2304 * 1024 * 2;  // vflat bytes
  const long sB_ = (long)NB * 2304 * 512 * 4;   // S bytes
  u16* vflatN = (u16*)chunk;
  float* SN   = (float*)(chunk + vfB);
  u16* Psum   = (u16*)(chunk + vfB + sB_);

  float* out0 = (float*)d_out;
  const long CN = 1024L * 2304;

  // merged cast Wq|Wk|t_tok + smallvecs (incl. folded softmax3)
  cast3_kernel<<<3968, 256, 0, stream>>>(Wq, Wk, t_tok, Wq16, Wk16, tt16);
  transpose_f32<<<dim3(12, 16, 1), 256, 0, stream>>>(Wv, WvT, 768, 1024, 0, 0);
  smallvecs_kernel<<<449, 256, 0, stream>>>(Wq, Wk, bq, bk, lam, hvec, uvec, wts);

  // GT(ci,t) = sum_co Wq(ci,co) * Wk(t,co)   : (1024, 768), K=1024
  gemm_nt<0, 0, false><<<dim3(8, 6, 1), 256, 0, stream>>>(
      Wq16, 0, 1024, Wk16, 0, 1024, GT, 0, 768, nullptr, nullptr, nullptr, 1.0f, 1024);
  // WkqT(l,ci) = sum_t tt16(l,t) * GT(ci,t) + h(ci)  : (8192, 1024), K=768
  gemm_nt<1, 0, false><<<dim3(64, 8, 1), 256, 0, stream>>>(
      tt16, 0, 768, GT, 0, 768, WkqT, 0, 1024, hvec, nullptr, nullptr, 1.0f, 768);
  // v_txtT(b) = Wv^T @ t_tok(b)^T + bv (per-m) : (1024,512) per batch, K=768
  gemm_nt<2, 0, false><<<dim3(8, 4, 16), 256, 0, stream>>>(
      WvT, 0, 768, tt16, 512L * 768, 768, vtxtT, 1024L * 512, 512, bv, nullptr, nullptr, 1.0f, 768);
  // bkq[b,l] = scale * (tt16[b,l,:].u + beta0)
  bkq_kernel<<<2048, 256, 0, stream>>>(tt16, uvec, bkq);

  for (int b0 = 0; b0 < 16; b0 += NB) {
    // vflat = transpose(v_feat NB-batch chunk) as bf16: (NB*N, C)
    transpose_f32<<<dim3(16, 36, NB), 256, 0, stream>>>(
        v_feat + b0 * CN, vflatN, 1024, 2304, CN, 2304L * 1024);
    // S = (vflat @ WkqT_b^T) / 32  (fp32, per batch), split-K2
    gemm_s_sk2<<<dim3(18, 4, NB), 512, 0, stream>>>(
        vflatN, 2304L * 1024, 1024, WkqT + (long)b0 * (512L * 1024), 512L * 1024, 1024,
        SN, 2304L * 512, 512, 0.03125f, 1024);
    // fused 25-tap pool + 3 softmaxes -> single weighted Psum (K=512 for PV)
    pool_sm<<<576 * NB, 256, 0, stream>>>(SN, bkq + (long)b0 * 512, Psum, wts);
    // out^T: out(c,n) = sum_l vtxtT(c,l) * Psum(n,l) + v_feat(c,n)
    gemm_nt<0, 3, false><<<dim3(8, 18, NB), 256, 0, stream>>>(
        vtxtT + (long)b0 * (1024L * 512), 1024L * 512, 512, Psum, 2304L * 512, 512,
        out0 + b0 * CN, CN, 2304, nullptr, v_feat + b0 * CN, nullptr, 1.0f, 512);
  }

  // out1 = t_tok (raw fp32 copy)
  hipMemcpyAsync((void*)(out0 + 37748736L), (const void*)t_tok, 25165824L,
                 hipMemcpyDeviceToDevice, stream);
}